// Round 2
// baseline (42.922 us; speedup 1.0000x reference)
//
#include <hip/hip_runtime.h>

#define NB 8
#define NS 2048
#define ND 768
#define ND4 192      // ND/4
#define SC 128       // S-chunks for the v column-sum
#define ROWS_PER_CHUNK (NS / SC)  // 16

typedef float f4 __attribute__((ext_vector_type(4)));

// ---------------- Kernel A: partial column-sums of v over S ----------------
// grid (SC, NB), block 192. Block (c,b) sums rows [c*16, c*16+16) of v[b].
// v is touched exactly once -> nontemporal loads (skip cache pollution).
__global__ __launch_bounds__(192) void vpart_kernel(const float* __restrict__ v,
                                                    float* __restrict__ part) {
    const int c = blockIdx.x;
    const int b = blockIdx.y;
    const int t = threadIdx.x;                 // 0..191  (one f4 column each)
    const f4* v4 = (const f4*)v + ((size_t)b * NS + (size_t)c * ROWS_PER_CHUNK) * ND4 + t;
    f4 acc = (f4)(0.f);
#pragma unroll
    for (int i = 0; i < ROWS_PER_CHUNK; ++i) {
        f4 x = __builtin_nontemporal_load(v4 + (size_t)i * ND4);
        acc += x;
    }
    // part stays cache-resident for kernel B -> normal store
    ((f4*)part)[((size_t)c * NB + b) * ND4 + t] = acc;
}

// ---------------- Kernel B: reduce the SC partials -> vsum[NB][ND] ----------------
// grid NB*ND/256, block 256. Deterministic sequential reduce (3 MB, L2/LLC-hot).
__global__ __launch_bounds__(256) void vreduce_kernel(const float* __restrict__ part,
                                                      float* __restrict__ vsum) {
    const int i = blockIdx.x * 256 + threadIdx.x;   // 0 .. NB*ND-1
    float acc = 0.f;
#pragma unroll 8
    for (int c = 0; c < SC; ++c) acc += part[(size_t)c * (NB * ND) + i];
    vsum[i] = acc;
}

// ---------------- Kernel C: hvec[b][d] = fc_w[d,:] . vsum[b,:] + fc_b[d] ----------------
// grid ND/4, block 256 (4 waves; wave w owns output row d = blk*4+w).
__global__ __launch_bounds__(256) void matvec_kernel(const float* __restrict__ fcw,
                                                     const float* __restrict__ fcb,
                                                     const float* __restrict__ vsum,
                                                     float* __restrict__ hvec) {
    __shared__ float lds[NB * ND];
    const int t = threadIdx.x;
    for (int i = t; i < NB * ND4; i += 256)
        ((f4*)lds)[i] = ((const f4*)vsum)[i];
    __syncthreads();

    const int w = t >> 6, l = t & 63;
    const int d = blockIdx.x * 4 + w;
    const f4* wrow = (const f4*)(fcw + (size_t)d * ND);
    float acc[NB] = {};
#pragma unroll
    for (int k = 0; k < 3; ++k) {
        const int e4 = l + k * 64;
        const f4 wv = wrow[e4];
#pragma unroll
        for (int b = 0; b < NB; ++b) {
            const f4 vs = ((const f4*)lds)[b * ND4 + e4];
            acc[b] += wv.x * vs.x + wv.y * vs.y + wv.z * vs.z + wv.w * vs.w;
        }
    }
#pragma unroll
    for (int off = 32; off >= 1; off >>= 1)
#pragma unroll
        for (int b = 0; b < NB; ++b)
            acc[b] += __shfl_down(acc[b], off, 64);
    if (l == 0) {
        const float bias = fcb[d];
#pragma unroll
        for (int b = 0; b < NB; ++b) hvec[b * ND + d] = acc[b] + bias;
    }
}

// ---------------- Kernel D: out = LayerNorm(q + hvec[b]) * g + beta ----------------
// grid NB*NS/8, block 256 (4 waves; TWO rows per wave for deeper MLP).
// q read once -> nontemporal loads; out written once -> nontemporal stores.
__global__ __launch_bounds__(256) void ln_kernel(const float* __restrict__ q,
                                                 const float* __restrict__ hvec,
                                                 const float* __restrict__ lng,
                                                 const float* __restrict__ lnb,
                                                 float* __restrict__ out) {
    const int w = threadIdx.x >> 6, l = threadIdx.x & 63;
    const int r0 = blockIdx.x * 8 + (w << 1);  // rows r0, r0+1 (same b: 8 | 2048)
    const int b = r0 >> 11;                    // row / NS
    const f4* qa = (const f4*)q + (size_t)r0 * ND4;
    const f4* qb = qa + ND4;
    const f4* h4 = (const f4*)hvec + (size_t)b * ND4;

    f4 xa[3], xb[3];
    float sa = 0.f, sqa = 0.f, sb = 0.f, sqb = 0.f;
#pragma unroll
    for (int k = 0; k < 3; ++k) {
        const int e4 = l + k * 64;
        const f4 qva = __builtin_nontemporal_load(qa + e4);
        const f4 qvb = __builtin_nontemporal_load(qb + e4);
        const f4 hv  = h4[e4];
        const f4 va = qva + hv;
        const f4 vb = qvb + hv;
        xa[k] = va; xb[k] = vb;
        sa  += va.x + va.y + va.z + va.w;
        sqa += va.x * va.x + va.y * va.y + va.z * va.z + va.w * va.w;
        sb  += vb.x + vb.y + vb.z + vb.w;
        sqb += vb.x * vb.x + vb.y * vb.y + vb.z * vb.z + vb.w * vb.w;
    }
#pragma unroll
    for (int off = 32; off >= 1; off >>= 1) {
        sa  += __shfl_xor(sa,  off, 64);
        sqa += __shfl_xor(sqa, off, 64);
        sb  += __shfl_xor(sb,  off, 64);
        sqb += __shfl_xor(sqb, off, 64);
    }
    const float inv = 1.0f / (float)ND;
    const float ma = sa * inv, mb = sb * inv;
    const float ra = rsqrtf(sqa * inv - ma * ma + 1e-5f);
    const float rb = rsqrtf(sqb * inv - mb * mb + 1e-5f);

    f4* oa = (f4*)out + (size_t)r0 * ND4;
    f4* ob = oa + ND4;
#pragma unroll
    for (int k = 0; k < 3; ++k) {
        const int e4 = l + k * 64;
        const f4 gv = ((const f4*)lng)[e4];
        const f4 bv = ((const f4*)lnb)[e4];
        f4 ova, ovb;
        ova.x = (xa[k].x - ma) * ra * gv.x + bv.x;
        ova.y = (xa[k].y - ma) * ra * gv.y + bv.y;
        ova.z = (xa[k].z - ma) * ra * gv.z + bv.z;
        ova.w = (xa[k].w - ma) * ra * gv.w + bv.w;
        ovb.x = (xb[k].x - mb) * rb * gv.x + bv.x;
        ovb.y = (xb[k].y - mb) * rb * gv.y + bv.y;
        ovb.z = (xb[k].z - mb) * rb * gv.z + bv.z;
        ovb.w = (xb[k].w - mb) * rb * gv.w + bv.w;
        __builtin_nontemporal_store(ova, oa + e4);
        __builtin_nontemporal_store(ovb, ob + e4);
    }
}

extern "C" void kernel_launch(void* const* d_in, const int* in_sizes, int n_in,
                              void* d_out, int out_size, void* d_ws, size_t ws_size,
                              hipStream_t stream) {
    // setup_inputs order: q, k, v, mask, fc_w, fc_b, ln_g, ln_b, index, typeAdd_Del
    const float* q   = (const float*)d_in[0];
    const float* v   = (const float*)d_in[2];
    const float* fcw = (const float*)d_in[4];
    const float* fcb = (const float*)d_in[5];
    const float* lng = (const float*)d_in[6];
    const float* lnb = (const float*)d_in[7];
    float* out = (float*)d_out;

    // workspace layout (all written before read each call; no cross-call state)
    float* part = (float*)d_ws;                 // SC*NB*ND floats = 3 MB
    float* vsum = part + (size_t)SC * NB * ND;  // NB*ND floats
    float* hvec = vsum + NB * ND;               // NB*ND floats

    vpart_kernel<<<dim3(SC, NB), 192, 0, stream>>>(v, part);
    vreduce_kernel<<<(NB * ND) / 256, 256, 0, stream>>>(part, vsum);
    matvec_kernel<<<ND / 4, 256, 0, stream>>>(fcw, fcb, vsum, hvec);
    ln_kernel<<<(NB * NS) / 8, 256, 0, stream>>>(q, hvec, lng, lnb, out);
}

// Round 3
// 40.817 us; speedup vs baseline: 1.0516x; 1.0516x over previous
//
#include <hip/hip_runtime.h>
#include <hip/hip_cooperative_groups.h>

namespace cg = cooperative_groups;

#define NB 8
#define NS 2048
#define ND 768
#define ND4 192      // ND/4
#define SC 128       // S-chunks for the v column-sum
#define RPC 16       // rows per chunk = NS/SC
#define GRID 1024    // = SC * NB
#define TPB 256

typedef float f4 __attribute__((ext_vector_type(4)));

// ================= fused cooperative kernel: all 4 phases =================
__global__ __launch_bounds__(TPB, 4) void fused_kernel(
    const float* __restrict__ q, const float* __restrict__ v,
    const float* __restrict__ fcw, const float* __restrict__ fcb,
    const float* __restrict__ lng, const float* __restrict__ lnb,
    float* __restrict__ part, float* __restrict__ vsum,
    float* __restrict__ hvec, float* __restrict__ out) {
    cg::grid_group grid = cg::this_grid();
    const int bb = blockIdx.x;
    const int t = threadIdx.x;

    // ---- P1: partial column-sums of v. block bb -> chunk c = bb>>3, batch b = bb&7
    {
        const int c = bb >> 3, b = bb & 7;
        if (t < ND4) {
            const f4* v4 = (const f4*)v + ((size_t)(b * NS + c * RPC)) * ND4 + t;
            f4 acc = (f4)(0.f);
#pragma unroll
            for (int i = 0; i < RPC; ++i)
                acc += __builtin_nontemporal_load(v4 + (size_t)i * ND4);
            ((f4*)part)[(size_t)bb * ND4 + t] = acc;   // part4[c*8+b][t]
        }
    }
    grid.sync();

    // ---- P2: reduce SC partials -> vsum[NB][ND]  (1536 f4 elements, 6 blocks)
    if (bb < 6) {
        const int idx = bb * TPB + t;                  // = b*192 + e4, 0..1535
        const f4* p4 = (const f4*)part;
        f4 acc = (f4)(0.f);
#pragma unroll 8
        for (int c = 0; c < SC; ++c) acc += p4[(size_t)c * 1536 + idx];
        ((f4*)vsum)[idx] = acc;
    }
    grid.sync();

    // ---- P3: hvec[b][d] = fc_w[d,:] . vsum[b,:] + fc_b[d]  (192 blocks)
    {
        __shared__ float lds[NB * ND];
        if (bb < 192) {
            for (int i = t; i < NB * ND4; i += TPB)
                ((f4*)lds)[i] = ((const f4*)vsum)[i];
            __syncthreads();
            const int w = t >> 6, l = t & 63;
            const int d = bb * 4 + w;
            const f4* wrow = (const f4*)(fcw + (size_t)d * ND);
            float acc[NB] = {};
#pragma unroll
            for (int k = 0; k < 3; ++k) {
                const int e4 = l + k * 64;
                const f4 wv = wrow[e4];
#pragma unroll
                for (int b = 0; b < NB; ++b) {
                    const f4 vs = ((const f4*)lds)[b * ND4 + e4];
                    acc[b] += wv.x * vs.x + wv.y * vs.y + wv.z * vs.z + wv.w * vs.w;
                }
            }
#pragma unroll
            for (int off = 32; off >= 1; off >>= 1)
#pragma unroll
                for (int b = 0; b < NB; ++b)
                    acc[b] += __shfl_down(acc[b], off, 64);
            if (l == 0) {
                const float bias = fcb[d];
#pragma unroll
                for (int b = 0; b < NB; ++b) hvec[b * ND + d] = acc[b] + bias;
            }
        }
    }
    grid.sync();

    // ---- P4: out = LayerNorm(q + hvec[b]) * g + beta. 16 rows/block, 2x2 rows/wave
    {
        const int w = t >> 6, l = t & 63;
#pragma unroll
        for (int j = 0; j < 2; ++j) {
            const int r0 = bb * 16 + w * 4 + j * 2;    // rows r0, r0+1 (same batch)
            const int b = r0 >> 11;
            const f4* qa = (const f4*)q + (size_t)r0 * ND4;
            const f4* qb = qa + ND4;
            const f4* h4 = (const f4*)hvec + (size_t)b * ND4;

            f4 xa[3], xb[3];
            float sa = 0.f, sqa = 0.f, sb = 0.f, sqb = 0.f;
#pragma unroll
            for (int k = 0; k < 3; ++k) {
                const int e4 = l + k * 64;
                const f4 qva = __builtin_nontemporal_load(qa + e4);
                const f4 qvb = __builtin_nontemporal_load(qb + e4);
                const f4 hv  = h4[e4];
                const f4 va = qva + hv;
                const f4 vb = qvb + hv;
                xa[k] = va; xb[k] = vb;
                sa  += va.x + va.y + va.z + va.w;
                sqa += va.x * va.x + va.y * va.y + va.z * va.z + va.w * va.w;
                sb  += vb.x + vb.y + vb.z + vb.w;
                sqb += vb.x * vb.x + vb.y * vb.y + vb.z * vb.z + vb.w * vb.w;
            }
#pragma unroll
            for (int off = 32; off >= 1; off >>= 1) {
                sa  += __shfl_xor(sa,  off, 64);
                sqa += __shfl_xor(sqa, off, 64);
                sb  += __shfl_xor(sb,  off, 64);
                sqb += __shfl_xor(sqb, off, 64);
            }
            const float inv = 1.0f / (float)ND;
            const float ma = sa * inv, mb = sb * inv;
            const float ra = rsqrtf(sqa * inv - ma * ma + 1e-5f);
            const float rb = rsqrtf(sqb * inv - mb * mb + 1e-5f);

            f4* oa = (f4*)out + (size_t)r0 * ND4;
            f4* ob = oa + ND4;
#pragma unroll
            for (int k = 0; k < 3; ++k) {
                const int e4 = l + k * 64;
                const f4 gv = ((const f4*)lng)[e4];
                const f4 bv = ((const f4*)lnb)[e4];
                f4 ova, ovb;
                ova.x = (xa[k].x - ma) * ra * gv.x + bv.x;
                ova.y = (xa[k].y - ma) * ra * gv.y + bv.y;
                ova.z = (xa[k].z - ma) * ra * gv.z + bv.z;
                ova.w = (xa[k].w - ma) * ra * gv.w + bv.w;
                ovb.x = (xb[k].x - mb) * rb * gv.x + bv.x;
                ovb.y = (xb[k].y - mb) * rb * gv.y + bv.y;
                ovb.z = (xb[k].z - mb) * rb * gv.z + bv.z;
                ovb.w = (xb[k].w - mb) * rb * gv.w + bv.w;
                __builtin_nontemporal_store(ova, oa + e4);
                __builtin_nontemporal_store(ovb, ob + e4);
            }
        }
    }
}

// ================= fallback path (4 separate kernels, proven in R1) =================
__global__ __launch_bounds__(192) void vpart_kernel(const float* __restrict__ v,
                                                    float* __restrict__ part) {
    const int c = blockIdx.x, b = blockIdx.y, t = threadIdx.x;
    const f4* v4 = (const f4*)v + ((size_t)b * NS + (size_t)c * RPC) * ND4 + t;
    f4 acc = (f4)(0.f);
#pragma unroll
    for (int i = 0; i < RPC; ++i) acc += v4[(size_t)i * ND4];
    ((f4*)part)[((size_t)c * NB + b) * ND4 + t] = acc;
}

__global__ __launch_bounds__(256) void vreduce_kernel(const float* __restrict__ part,
                                                      float* __restrict__ vsum) {
    const int i = blockIdx.x * 256 + threadIdx.x;
    float acc = 0.f;
#pragma unroll 8
    for (int c = 0; c < SC; ++c) acc += part[(size_t)c * (NB * ND) + i];
    vsum[i] = acc;
}

__global__ __launch_bounds__(256) void matvec_kernel(const float* __restrict__ fcw,
                                                     const float* __restrict__ fcb,
                                                     const float* __restrict__ vsum,
                                                     float* __restrict__ hvec) {
    __shared__ float lds[NB * ND];
    const int t = threadIdx.x;
    for (int i = t; i < NB * ND4; i += 256)
        ((f4*)lds)[i] = ((const f4*)vsum)[i];
    __syncthreads();
    const int w = t >> 6, l = t & 63;
    const int d = blockIdx.x * 4 + w;
    const f4* wrow = (const f4*)(fcw + (size_t)d * ND);
    float acc[NB] = {};
#pragma unroll
    for (int k = 0; k < 3; ++k) {
        const int e4 = l + k * 64;
        const f4 wv = wrow[e4];
#pragma unroll
        for (int b = 0; b < NB; ++b) {
            const f4 vs = ((const f4*)lds)[b * ND4 + e4];
            acc[b] += wv.x * vs.x + wv.y * vs.y + wv.z * vs.z + wv.w * vs.w;
        }
    }
#pragma unroll
    for (int off = 32; off >= 1; off >>= 1)
#pragma unroll
        for (int b = 0; b < NB; ++b) acc[b] += __shfl_down(acc[b], off, 64);
    if (l == 0) {
        const float bias = fcb[d];
#pragma unroll
        for (int b = 0; b < NB; ++b) hvec[b * ND + d] = acc[b] + bias;
    }
}

__global__ __launch_bounds__(256) void ln_kernel(const float* __restrict__ q,
                                                 const float* __restrict__ hvec,
                                                 const float* __restrict__ lng,
                                                 const float* __restrict__ lnb,
                                                 float* __restrict__ out) {
    const int w = threadIdx.x >> 6, l = threadIdx.x & 63;
    const int r0 = blockIdx.x * 8 + (w << 1);
    const int b = r0 >> 11;
    const f4* qa = (const f4*)q + (size_t)r0 * ND4;
    const f4* qb = qa + ND4;
    const f4* h4 = (const f4*)hvec + (size_t)b * ND4;
    f4 xa[3], xb[3];
    float sa = 0.f, sqa = 0.f, sb = 0.f, sqb = 0.f;
#pragma unroll
    for (int k = 0; k < 3; ++k) {
        const int e4 = l + k * 64;
        const f4 qva = qa[e4], qvb = qb[e4], hv = h4[e4];
        const f4 va = qva + hv, vb = qvb + hv;
        xa[k] = va; xb[k] = vb;
        sa  += va.x + va.y + va.z + va.w;
        sqa += va.x * va.x + va.y * va.y + va.z * va.z + va.w * va.w;
        sb  += vb.x + vb.y + vb.z + vb.w;
        sqb += vb.x * vb.x + vb.y * vb.y + vb.z * vb.z + vb.w * vb.w;
    }
#pragma unroll
    for (int off = 32; off >= 1; off >>= 1) {
        sa += __shfl_xor(sa, off, 64); sqa += __shfl_xor(sqa, off, 64);
        sb += __shfl_xor(sb, off, 64); sqb += __shfl_xor(sqb, off, 64);
    }
    const float inv = 1.0f / (float)ND;
    const float ma = sa * inv, mb = sb * inv;
    const float ra = rsqrtf(sqa * inv - ma * ma + 1e-5f);
    const float rb = rsqrtf(sqb * inv - mb * mb + 1e-5f);
    f4* oa = (f4*)out + (size_t)r0 * ND4;
    f4* ob = oa + ND4;
#pragma unroll
    for (int k = 0; k < 3; ++k) {
        const int e4 = l + k * 64;
        const f4 gv = ((const f4*)lng)[e4];
        const f4 bv = ((const f4*)lnb)[e4];
        f4 ova, ovb;
        ova.x = (xa[k].x - ma) * ra * gv.x + bv.x;
        ova.y = (xa[k].y - ma) * ra * gv.y + bv.y;
        ova.z = (xa[k].z - ma) * ra * gv.z + bv.z;
        ova.w = (xa[k].w - ma) * ra * gv.w + bv.w;
        ovb.x = (xb[k].x - mb) * rb * gv.x + bv.x;
        ovb.y = (xb[k].y - mb) * rb * gv.y + bv.y;
        ovb.z = (xb[k].z - mb) * rb * gv.z + bv.z;
        ovb.w = (xb[k].w - mb) * rb * gv.w + bv.w;
        oa[e4] = ova; ob[e4] = ovb;
    }
}

extern "C" void kernel_launch(void* const* d_in, const int* in_sizes, int n_in,
                              void* d_out, int out_size, void* d_ws, size_t ws_size,
                              hipStream_t stream) {
    // setup_inputs order: q, k, v, mask, fc_w, fc_b, ln_g, ln_b, index, typeAdd_Del
    const float* q   = (const float*)d_in[0];
    const float* v   = (const float*)d_in[2];
    const float* fcw = (const float*)d_in[4];
    const float* fcb = (const float*)d_in[5];
    const float* lng = (const float*)d_in[6];
    const float* lnb = (const float*)d_in[7];
    float* out = (float*)d_out;

    float* part = (float*)d_ws;                 // SC*NB*ND floats = 3 MB
    float* vsum = part + (size_t)SC * NB * ND;  // NB*ND floats
    float* hvec = vsum + NB * ND;               // NB*ND floats

    // host-side occupancy check (pure query, graph-capture safe, deterministic)
    int blocksPerCU = 0;
    (void)hipOccupancyMaxActiveBlocksPerMultiprocessor(&blocksPerCU,
        (const void*)fused_kernel, TPB, 0);
    static int numCU = 0;
    if (numCU == 0) {
        hipDeviceProp_t prop;
        (void)hipGetDeviceProperties(&prop, 0);
        numCU = prop.multiProcessorCount;
    }

    if (blocksPerCU * numCU >= GRID) {
        void* args[] = {(void*)&q, (void*)&v, (void*)&fcw, (void*)&fcb,
                        (void*)&lng, (void*)&lnb, (void*)&part, (void*)&vsum,
                        (void*)&hvec, (void*)&out};
        (void)hipLaunchCooperativeKernel((const void*)fused_kernel, dim3(GRID),
                                         dim3(TPB), args, 0, stream);
    } else {
        vpart_kernel<<<dim3(SC, NB), 192, 0, stream>>>(v, part);
        vreduce_kernel<<<(NB * ND) / 256, 256, 0, stream>>>(part, vsum);
        matvec_kernel<<<ND / 4, 256, 0, stream>>>(fcw, fcb, vsum, hvec);
        ln_kernel<<<(NB * NS) / 8, 256, 0, stream>>>(q, hvec, lng, lnb, out);
    }
}